// Round 6
// baseline (842.968 us; speedup 1.0000x reference)
//
#include <hip/hip_runtime.h>

#define BINS   10
#define CSHIFT 26
#define QMASK  0x03FFFFFFu
#define QSCALE 2097152.0f        // 2^21 quanta per loss unit
#define QLN2   1453635.25f       // ln2 * 2^21: q = round(log2(1+em) * QLN2)
#define GRID   4096
#define TPB    256

// ws layout (CUMULATIVE over bins): float qsum[10] @ word 0, u32 cnt[10] @ word
// 16, u32 done-counter @ word 31. Re-poisoned 0xAA each replay -> zero each launch.

__global__ void ghm_zero_ws(unsigned* ws) {
    if (threadIdx.x < 32) ws[threadIdx.x] = 0u;
}

// bin b <=> D[b+1] < d <= D[b], D[b] = ln(20/b - 1); cumulative A[b] over d>Th[b].
__device__ __forceinline__ void proc1(float o0, float o1, int t, unsigned* A) {
    const float Th[BINS] = {
        2.9444390f, 2.1972246f, 1.7346011f, 1.3862944f, 1.0986123f,
        0.8472979f, 0.6190392f, 0.4054651f, 0.2006707f, 0.0f };
    float s = o0 - o1;
    float d = __int_as_float(__float_as_int(s) ^ (t << 31));  // target - other
    float em   = __expf(-d);
    float qf   = fmaf(__log2f(1.0f + em), QLN2, 0.5f);  // round(loss * 2^21)
    unsigned val = (unsigned)qf + (1u << CSHIFT);       // d<=0: masked below
    #pragma unroll
    for (int b = 0; b < BINS; ++b)
        A[b] += (d > Th[b]) ? val : 0u;
}

__global__ __launch_bounds__(TPB, 4)
void ghm_main(const float* __restrict__ outs,   // [n,2]
              const int*   __restrict__ tgt,    // [n]
              float*       __restrict__ ws_q,   // cumulative loss sums (loss units)
              unsigned*    __restrict__ ws_c,   // cumulative counts
              unsigned*    __restrict__ ws_done,
              const float* __restrict__ acc_sum,
              float*       __restrict__ out,
              int n) {
    const int tid  = threadIdx.x;
    const int lane = tid & 63;
    const int wv   = tid >> 6;

    unsigned A[BINS];
    #pragma unroll
    for (int b = 0; b < BINS; ++b) A[b] = 0u;

    // Unit = 2 samples = one float4 + one int2. Wave w owns units
    // [w*512, w*512+512) as 8 chunks of 64 — every load is unit-stride,
    // single-touch, 1 KB (outs) / 512 B (tgt) per wave-instruction.
    const int nunits  = n >> 1;
    const int wave_id = blockIdx.x * (TPB / 64) + wv;
    const int base    = wave_id * 512;

    const float4* outs4 = (const float4*)outs;
    const int2*   tgt2  = (const int2*)tgt;

    if (base + 512 <= nunits) {
        float4 o[8]; int2 t[8];
        #pragma unroll
        for (int c = 0; c < 8; ++c) {           // all 16 loads in flight up front
            int u = base + c * 64 + lane;
            o[c] = outs4[u];
            t[c] = tgt2[u];
        }
        #pragma unroll
        for (int c = 0; c < 8; ++c) {
            proc1(o[c].x, o[c].y, t[c].x, A);
            proc1(o[c].z, o[c].w, t[c].y, A);
        }
    } else {                                    // ragged tail (unused at N=2^24)
        for (int c = 0; c < 8; ++c) {
            int u = base + c * 64 + lane;
            if (u < nunits) {
                float4 o = outs4[u];
                int2   t = tgt2[u];
                proc1(o.x, o.y, t.x, A);
                proc1(o.z, o.w, t.y, A);
            }
        }
    }
    if ((n & 1) && wave_id == 0 && lane == 0)   // odd-n last sample (unused here)
        proc1(outs[2 * (n - 1)], outs[2 * (n - 1) + 1], tgt[n - 1], A);

    // ---- block reduction: dump packed regs to LDS once, tree-reduce ----
    __shared__ unsigned h[BINS][256];           // 10 KB
    __shared__ unsigned s_c[BINS][16];
    __shared__ float    s_q[BINS][16];
    __shared__ unsigned s_last;
    __shared__ float    f_q[BINS];
    __shared__ unsigned f_c[BINS];

    #pragma unroll
    for (int b = 0; b < BINS; ++b) h[b][tid] = A[b];
    __syncthreads();

    if (tid < 16 * BINS) {
        int bin  = tid >> 4;
        int part = tid & 15;
        unsigned c = 0, q = 0;                  // q <= 16*16*ln2*2^21 < 2^32
        #pragma unroll
        for (int j = 0; j < 16; ++j) {
            unsigned v = h[bin][j * 16 + part];
            c += v >> CSHIFT;
            q += v & QMASK;
        }
        s_c[bin][part] = c;
        s_q[bin][part] = (float)q;
    }
    __syncthreads();
    if (tid < BINS) {
        unsigned c = 0; float q = 0.0f;
        #pragma unroll
        for (int j = 0; j < 16; ++j) { c += s_c[tid][j]; q += s_q[tid][j]; }
        if (c) {
            atomicAdd(&ws_c[tid], c);
            atomicAdd(&ws_q[tid], q * (1.0f / QSCALE));
        }
    }

    // ---- last-block-done finalize (replaces the ghm_final launch) ----
    __threadfence();                            // order partials before counter
    __syncthreads();
    if (tid == 0)
        s_last = (atomicAdd(ws_done, 1u) == (unsigned)(gridDim.x - 1)) ? 1u : 0u;
    __syncthreads();
    if (s_last) {                               // block-uniform
        __threadfence();
        if (tid < BINS) {                       // coherent reads via atomic RMW
            f_q[tid] = atomicAdd(&ws_q[tid], 0.0f);
            f_c[tid] = atomicAdd(&ws_c[tid], 0u);
        }
        __syncthreads();
        if (tid == 0) {
            float r = 0.0f, pq = 0.0f;
            unsigned pc = 0u;
            #pragma unroll
            for (int b = 0; b < BINS; ++b) {    // cumulative -> per-bin diff
                unsigned cnt = f_c[b] - pc;
                float    qs  = f_q[b] - pq;
                pc = f_c[b]; pq = f_q[b];
                if (cnt > 0u) {
                    float na = 0.75f * acc_sum[b] + 0.25f * (float)cnt;
                    r += qs / na;   // = (1/N) * sum(loss_i * N/na[bin_i])
                }
            }
            *out = r;
        }
    }
}

extern "C" void kernel_launch(void* const* d_in, const int* in_sizes, int n_in,
                              void* d_out, int out_size, void* d_ws, size_t ws_size,
                              hipStream_t stream) {
    const float* outputs = (const float*)d_in[0];  // [N,2] f32
    const int*   targets = (const int*)d_in[1];    // [N] int32
    const float* acc_sum = (const float*)d_in[2];  // [10] f32
    int n = in_sizes[1];

    float*    ws_q    = (float*)d_ws;
    unsigned* ws_c    = (unsigned*)((char*)d_ws + 64);
    unsigned* ws_done = (unsigned*)((char*)d_ws + 124);

    ghm_zero_ws<<<1, 64, 0, stream>>>((unsigned*)d_ws);
    ghm_main<<<GRID, TPB, 0, stream>>>(outputs, targets, ws_q, ws_c, ws_done,
                                       acc_sum, (float*)d_out, n);
}

// Round 7
// 244.861 us; speedup vs baseline: 3.4426x; 3.4426x over previous
//
#include <hip/hip_runtime.h>

#define BINS   10
#define CSHIFT 26
#define QMASK  0x03FFFFFFu
#define QSCALE 2097152.0f        // 2^21 quanta per loss unit
#define QLN2   1453635.25f       // ln2 * 2^21: q = round(log2(1+em) * QLN2)
#define GRID   4096
#define TPB    256

// ws layout (CUMULATIVE over bins): float qsum[10] @ byte 0, u32 cnt[10] @ 64.
// Re-poisoned 0xAA each replay -> zero each launch.

__global__ void ghm_zero_ws(unsigned* ws) {
    if (threadIdx.x < 32) ws[threadIdx.x] = 0u;
}

// bin b <=> D[b+1] < d <= D[b], D[b] = ln(20/b - 1); cumulative A[b] over d>Th[b].
__device__ __forceinline__ void proc1(float o0, float o1, int t, unsigned* A) {
    const float Th[BINS] = {
        2.9444390f, 2.1972246f, 1.7346011f, 1.3862944f, 1.0986123f,
        0.8472979f, 0.6190392f, 0.4054651f, 0.2006707f, 0.0f };
    float s = o0 - o1;
    float d = __int_as_float(__float_as_int(s) ^ (t << 31));  // target - other
    float em = __expf(-d);
    float qf = fmaf(__log2f(1.0f + em), QLN2, 0.5f);  // round(loss * 2^21)
    unsigned val = (unsigned)qf + (1u << CSHIFT);     // d<=0 lanes: masked below
    #pragma unroll
    for (int b = 0; b < BINS; ++b)
        A[b] += (d > Th[b]) ? val : 0u;
}

__global__ __launch_bounds__(TPB, 4)
void ghm_main(const float* __restrict__ outs,   // [n,2]
              const int*   __restrict__ tgt,    // [n]
              float*       __restrict__ ws_q,
              unsigned*    __restrict__ ws_c,
              int n) {
    const int tid  = threadIdx.x;
    const int lane = tid & 63;
    const int wv   = tid >> 6;

    unsigned A[BINS];
    #pragma unroll
    for (int b = 0; b < BINS; ++b) A[b] = 0u;

    // Unit = 2 samples = one float4 + one int2. Wave owns 512 consecutive
    // units as 8 chunks of 64: every load is unit-stride, single-touch,
    // 1 KB (outs) / 512 B (tgt) per wave-instruction.
    const int nunits  = n >> 1;
    const int wave_id = blockIdx.x * (TPB / 64) + wv;
    const int base    = wave_id * 512;

    const float4* outs4 = (const float4*)outs;
    const int2*   tgt2  = (const int2*)tgt;

    if (base + 512 <= nunits) {
        float4 o[8]; int2 t[8];
        #pragma unroll
        for (int c = 0; c < 8; ++c) {           // 16 loads, 12 KB/wave in flight
            int u = base + c * 64 + lane;
            o[c] = outs4[u];
            t[c] = tgt2[u];
        }
        __builtin_amdgcn_sched_barrier(0);      // no compute hoisted above loads:
                                                // forces all 16 issued up front
        #pragma unroll
        for (int c = 0; c < 8; ++c) {
            proc1(o[c].x, o[c].y, t[c].x, A);
            proc1(o[c].z, o[c].w, t[c].y, A);
        }
    } else {                                    // ragged tail (unused at N=2^24)
        for (int c = 0; c < 8; ++c) {
            int u = base + c * 64 + lane;
            if (u < nunits) {
                float4 o = outs4[u];
                int2   t = tgt2[u];
                proc1(o.x, o.y, t.x, A);
                proc1(o.z, o.w, t.y, A);
            }
        }
    }
    if ((n & 1) && wave_id == 0 && lane == 0)   // odd-n last sample (unused here)
        proc1(outs[2 * (n - 1)], outs[2 * (n - 1) + 1], tgt[n - 1], A);

    // ---- block reduction: dump packed regs to LDS once, tree-reduce ----
    __shared__ unsigned h[BINS][256];           // 10 KB
    __shared__ unsigned s_c[BINS][16];
    __shared__ float    s_q[BINS][16];
    #pragma unroll
    for (int b = 0; b < BINS; ++b) h[b][tid] = A[b];
    __syncthreads();

    if (tid < 16 * BINS) {
        int bin  = tid >> 4;
        int part = tid & 15;
        unsigned c = 0, q = 0;                  // q <= 16*16*ln2*2^21 < 2^32
        #pragma unroll
        for (int j = 0; j < 16; ++j) {
            unsigned v = h[bin][j * 16 + part];
            c += v >> CSHIFT;
            q += v & QMASK;
        }
        s_c[bin][part] = c;
        s_q[bin][part] = (float)q;
    }
    __syncthreads();
    if (tid < BINS) {
        unsigned c = 0; float q = 0.0f;
        #pragma unroll
        for (int j = 0; j < 16; ++j) { c += s_c[tid][j]; q += s_q[tid][j]; }
        if (c) {                                // fire-and-forget, 20 addrs total
            atomicAdd(&ws_c[tid], c);
            atomicAdd(&ws_q[tid], q * (1.0f / QSCALE));
        }
    }
}

__global__ void ghm_final(const float*    __restrict__ ws_q,
                          const unsigned* __restrict__ ws_c,
                          const float*    __restrict__ acc_sum,
                          float* __restrict__ out) {
    if (threadIdx.x == 0) {
        float r = 0.0f, pq = 0.0f;
        unsigned pc = 0u;
        #pragma unroll
        for (int b = 0; b < BINS; ++b) {        // cumulative -> per-bin diff
            float    cq = ws_q[b];
            unsigned cc = ws_c[b];
            unsigned cnt = cc - pc;
            float    qs  = cq - pq;
            pc = cc; pq = cq;
            if (cnt > 0u) {
                float na = 0.75f * acc_sum[b] + 0.25f * (float)cnt;
                r += qs / na;    // = (1/N) * sum(loss_i * N/na[bin_i])
            }
        }
        *out = r;
    }
}

extern "C" void kernel_launch(void* const* d_in, const int* in_sizes, int n_in,
                              void* d_out, int out_size, void* d_ws, size_t ws_size,
                              hipStream_t stream) {
    const float* outputs = (const float*)d_in[0];  // [N,2] f32
    const int*   targets = (const int*)d_in[1];    // [N] int32
    const float* acc_sum = (const float*)d_in[2];  // [10] f32
    int n = in_sizes[1];

    float*    ws_q = (float*)d_ws;
    unsigned* ws_c = (unsigned*)((char*)d_ws + 64);

    ghm_zero_ws<<<1, 64, 0, stream>>>((unsigned*)d_ws);
    ghm_main<<<GRID, TPB, 0, stream>>>(outputs, targets, ws_q, ws_c, n);
    ghm_final<<<1, 64, 0, stream>>>(ws_q, ws_c, acc_sum, (float*)d_out);
}

// Round 8
// 241.349 us; speedup vs baseline: 3.4927x; 1.0146x over previous
//
#include <hip/hip_runtime.h>

#define BINS   10
#define CSHIFT 26
#define QMASK  0x03FFFFFFu
#define QSCALE 2097152.0f        // 2^21 quanta per loss unit
#define QLN2   1453635.25f       // ln2 * 2^21: q = round(log2(1+em) * QLN2)
#define GRID   1536              // 6 blocks/CU co-resident (24 KB LDS each)
#define TPB    256
#define TILE   1024              // samples per tile: 8 KB outs + 4 KB tgt

// ws layout (CUMULATIVE over bins): float qsum[10] @ byte 0, u32 cnt[10] @ 64.
// Re-poisoned 0xAA each replay -> zero each launch.

__global__ void ghm_zero_ws(unsigned* ws) {
    if (threadIdx.x < 32) ws[threadIdx.x] = 0u;
}

// Async global->LDS DMA, 16 B/lane. LDS dest = wave-uniform base + lane*16.
__device__ __forceinline__ void gld_lds16(const void* g, void* l) {
    __builtin_amdgcn_global_load_lds(
        (const __attribute__((address_space(1))) void*)g,
        (__attribute__((address_space(3))) void*)l, 16, 0, 0);
}

// bin b <=> D[b+1] < d <= D[b], D[b] = ln(20/b - 1); cumulative A[b] over d>Th[b].
__device__ __forceinline__ void proc1(float o0, float o1, int t, unsigned* A) {
    const float Th[BINS] = {
        2.9444390f, 2.1972246f, 1.7346011f, 1.3862944f, 1.0986123f,
        0.8472979f, 0.6190392f, 0.4054651f, 0.2006707f, 0.0f };
    float s = o0 - o1;
    float d = __int_as_float(__float_as_int(s) ^ (t << 31));  // target - other
    float em = __expf(-d);
    float qf = fmaf(__log2f(1.0f + em), QLN2, 0.5f);  // round(loss * 2^21)
    unsigned val = (unsigned)qf + (1u << CSHIFT);     // d<=0 lanes: masked below
    #pragma unroll
    for (int b = 0; b < BINS; ++b)
        A[b] += (d > Th[b]) ? val : 0u;
}

__global__ __launch_bounds__(TPB, 6)
void ghm_main(const float* __restrict__ outs,   // [n,2]
              const int*   __restrict__ tgt,    // [n]
              float*       __restrict__ ws_q,
              unsigned*    __restrict__ ws_c,
              int n) {
    // Staging buffers union'd with epilogue scratch (never live together).
    __shared__ union {
        struct {
            unsigned char o[2][TILE * 8];      // 2 x 8 KB, global byte order
            unsigned char t[2][TILE * 4];      // 2 x 4 KB
        } st;
        struct {
            unsigned h[BINS][256];             // 10 KB
            unsigned c[BINS][16];
            float    q[BINS][16];
        } ep;
    } sh;                                      // 24 KB

    const int tid  = threadIdx.x;
    const int lane = tid & 63;
    const int wv   = tid >> 6;

    unsigned A[BINS];
    #pragma unroll
    for (int b = 0; b < BINS; ++b) A[b] = 0u;

    const int ntiles = n >> 10;                // full 1024-sample tiles

    // Stage tile -> buffer pb: per wave 2x1KB outs + 1x1KB tgt DMA issues.
    const char* outs_b = (const char*)outs;
    const char* tgt_b  = (const char*)tgt;
    #define STAGE(tile, pb)                                                     \
        do {                                                                    \
            const char* go = outs_b + ((size_t)(tile) << 13) + (wv << 11)       \
                             + (lane << 4);                                     \
            char*       lo = (char*)sh.st.o[pb] + (wv << 11);                   \
            gld_lds16(go, lo);                                                  \
            gld_lds16(go + 1024, lo + 1024);                                    \
            const char* gt = tgt_b + ((size_t)(tile) << 12) + (wv << 10)        \
                             + (lane << 4);                                     \
            gld_lds16(gt, (char*)sh.st.t[pb] + (wv << 10));                     \
        } while (0)

    int t  = blockIdx.x;
    int pb = 0;
    if (t < ntiles) STAGE(t, 0);
    __syncthreads();                           // tile t resident

    for (; t < ntiles; t += gridDim.x) {
        int tn = t + gridDim.x;
        if (tn < ntiles) STAGE(tn, pb ^ 1);    // async: overlaps consume below

        const float4* o4 = (const float4*)sh.st.o[pb];
        const int4*   t4 = (const int4*)sh.st.t[pb];
        float4 a  = o4[2 * tid];
        float4 bq = o4[2 * tid + 1];
        int4   tv = t4[tid];
        proc1(a.x,  a.y,  tv.x, A);
        proc1(a.z,  a.w,  tv.y, A);
        proc1(bq.x, bq.y, tv.z, A);
        proc1(bq.z, bq.w, tv.w, A);

        __syncthreads();                       // drains next-tile DMA too
        pb ^= 1;
    }

    // tail samples (n % 1024; zero at N=2^24) — block 0, direct from global
    int rem = ntiles << 10;
    if (blockIdx.x == 0) {
        for (int s = rem + tid; s < n; s += TPB)
            proc1(outs[2 * s], outs[2 * s + 1], tgt[s], A);
    }

    // ---- epilogue: dump packed regs, tree-reduce, 20 atomics/block ----
    __syncthreads();                           // staging reads fully done
    #pragma unroll
    for (int b = 0; b < BINS; ++b) sh.ep.h[b][tid] = A[b];
    __syncthreads();

    if (tid < 16 * BINS) {
        int bin  = tid >> 4;
        int part = tid & 15;
        unsigned c = 0, q = 0;                 // q <= 16*44*ln2*2^21 ~ 1.0e9 < 2^32
        #pragma unroll
        for (int j = 0; j < 16; ++j) {
            unsigned v = sh.ep.h[bin][j * 16 + part];
            c += v >> CSHIFT;
            q += v & QMASK;
        }
        sh.ep.c[bin][part] = c;
        sh.ep.q[bin][part] = (float)q;
    }
    __syncthreads();
    if (tid < BINS) {
        unsigned c = 0; float q = 0.0f;
        #pragma unroll
        for (int j = 0; j < 16; ++j) { c += sh.ep.c[tid][j]; q += sh.ep.q[tid][j]; }
        if (c) {                               // fire-and-forget, 20 addrs total
            atomicAdd(&ws_c[tid], c);
            atomicAdd(&ws_q[tid], q * (1.0f / QSCALE));
        }
    }
}

__global__ void ghm_final(const float*    __restrict__ ws_q,
                          const unsigned* __restrict__ ws_c,
                          const float*    __restrict__ acc_sum,
                          float* __restrict__ out) {
    if (threadIdx.x == 0) {
        float r = 0.0f, pq = 0.0f;
        unsigned pc = 0u;
        #pragma unroll
        for (int b = 0; b < BINS; ++b) {       // cumulative -> per-bin diff
            float    cq = ws_q[b];
            unsigned cc = ws_c[b];
            unsigned cnt = cc - pc;
            float    qs  = cq - pq;
            pc = cc; pq = cq;
            if (cnt > 0u) {
                float na = 0.75f * acc_sum[b] + 0.25f * (float)cnt;
                r += qs / na;    // = (1/N) * sum(loss_i * N/na[bin_i])
            }
        }
        *out = r;
    }
}

extern "C" void kernel_launch(void* const* d_in, const int* in_sizes, int n_in,
                              void* d_out, int out_size, void* d_ws, size_t ws_size,
                              hipStream_t stream) {
    const float* outputs = (const float*)d_in[0];  // [N,2] f32
    const int*   targets = (const int*)d_in[1];    // [N] int32
    const float* acc_sum = (const float*)d_in[2];  // [10] f32
    int n = in_sizes[1];

    float*    ws_q = (float*)d_ws;
    unsigned* ws_c = (unsigned*)((char*)d_ws + 64);

    ghm_zero_ws<<<1, 64, 0, stream>>>((unsigned*)d_ws);
    ghm_main<<<GRID, TPB, 0, stream>>>(outputs, targets, ws_q, ws_c, n);
    ghm_final<<<1, 64, 0, stream>>>(ws_q, ws_c, acc_sum, (float*)d_out);
}